// Round 13
// baseline (173.184 us; speedup 1.0000x reference)
//
#include <hip/hip_runtime.h>
#include <hip/hip_bf16.h>
#include <math.h>

// Problem constants: B=16, C=OUP=64, H=W=128, HW=16384, M=10
#define NB   16
#define NC   64
#define NH   128
#define NW   128
#define NHW  16384
#define NM   10
#define XCS  16416   // padded xc plane stride (elements)

// ---------------------------------------------------------------------------
// K0: g[b,c] = mean over HW of x[b,c,:,:]   (f64 accumulation, float4 loads)
// FROZEN (bit-exact g).
// ---------------------------------------------------------------------------
__global__ __launch_bounds__(256) void k_gmean(const float* __restrict__ x,
                                               double* __restrict__ g) {
    int bc = blockIdx.x;                     // 0..1023
    const float* xp = x + (size_t)bc * NHW;
    double s = 0.0;
    for (int i = threadIdx.x; i < NHW / 4; i += 256) {
        float4 v = ((const float4*)xp)[i];
        s += (double)v.x + (double)v.y + (double)v.z + (double)v.w;
    }
    for (int off = 32; off; off >>= 1) s += __shfl_down(s, off);
    __shared__ double red[4];
    int wid = threadIdx.x >> 6, lane = threadIdx.x & 63;
    if (lane == 0) red[wid] = s;
    __syncthreads();
    if (threadIdx.x == 0)
        g[bc] = (red[0] + red[1] + red[2] + red[3]) * (1.0 / (double)NHW);
}

// ---------------------------------------------------------------------------
// K0b: block 0 transposes W -> Wt[c][o]; blocks 1..16 compute gn[b].
// ---------------------------------------------------------------------------
__global__ __launch_bounds__(256) void k_misc(const float* __restrict__ W,
                                              const double* __restrict__ g,
                                              float* __restrict__ Wt,
                                              double* __restrict__ gn) {
    if (blockIdx.x == 0) {
        for (int e = threadIdx.x; e < 64 * 64; e += 256) {
            int c = e >> 6, o = e & 63;
            Wt[c * 64 + o] = W[o * 64 + c];
        }
    } else if (threadIdx.x == 0) {
        int b = blockIdx.x - 1;
        const double* gb = g + b * NC;
        double gsq = 0.0;
        for (int c = 0; c < NC; ++c) gsq += gb[c] * gb[c];
        gn[b] = fmax(sqrt(gsq), 1e-8);
    }
}

// ---------------------------------------------------------------------------
// K1a: cosine-sim S + per-block min/max partials.  STREAMED loads (no xv
// array), 4-way-split f64 chains -> ~30 VGPR, 8 waves/SIMD.
// ---------------------------------------------------------------------------
__global__ __launch_bounds__(256) void k_S(
        const float* __restrict__ x, const double* __restrict__ g,
        const double* __restrict__ gn, double* __restrict__ S,
        double* __restrict__ pmn, double* __restrict__ pmx) {
    int bid = blockIdx.x;
    int P = bid * 256 + threadIdx.x;
    int b = P >> 14, k = P & (NHW - 1);
    const float* xb = x + (size_t)b * NC * NHW + k;
    const double* gb = g + b * NC;

    double n0 = 0.0, n1 = 0.0, n2 = 0.0, n3 = 0.0;
    double q0 = 0.0, q1 = 0.0, q2 = 0.0, q3 = 0.0;
#pragma unroll 4
    for (int c = 0; c < NC; c += 4) {
        double v0 = (double)xb[(size_t)(c+0) * NHW];
        double v1 = (double)xb[(size_t)(c+1) * NHW];
        double v2 = (double)xb[(size_t)(c+2) * NHW];
        double v3 = (double)xb[(size_t)(c+3) * NHW];
        n0 += gb[c+0] * v0;  q0 += v0 * v0;
        n1 += gb[c+1] * v1;  q1 += v1 * v1;
        n2 += gb[c+2] * v2;  q2 += v2 * v2;
        n3 += gb[c+3] * v3;  q3 += v3 * v3;
    }
    double num = (n0 + n1) + (n2 + n3);
    double sq  = (q0 + q1) + (q2 + q3);
    double xn = fmax(sqrt(sq), 1e-8);
    double Sv = num / (gn[b] * xn);
    S[P] = Sv;

    // block min/max partials (fmin/fmax exact -> order-independent)
    double mn = Sv, mx = Sv;
    for (int off = 32; off; off >>= 1) {
        mn = fmin(mn, __shfl_down(mn, off));
        mx = fmax(mx, __shfl_down(mx, off));
    }
    __shared__ double rmn[4], rmx[4];
    int wid = threadIdx.x >> 6, lane = threadIdx.x & 63;
    if (lane == 0) { rmn[wid] = mn; rmx[wid] = mx; }
    __syncthreads();
    if (threadIdx.x == 0) {
        pmn[bid] = fmin(fmin(rmn[0], rmn[1]), fmin(rmn[2], rmn[3]));
        pmx[bid] = fmax(fmax(rmx[0], rmx[1]), fmax(rmx[2], rmx[3]));
    }
}

// ---------------------------------------------------------------------------
// K1b: 1x1 conv GEMM.  Thread = (pixel, 16-output group); x streamed
// (re-read 4x, L3-resident); W via wave-uniform s_load.  ~30 VGPR.
// ---------------------------------------------------------------------------
__global__ __launch_bounds__(256) void k_conv(
        const float* __restrict__ x, const float* __restrict__ Wt,
        float* __restrict__ xc) {
    int o0 = blockIdx.y * 16;
    int P = blockIdx.x * 256 + threadIdx.x;
    int b = P >> 14, k = P & (NHW - 1);
    const float* xb = x + (size_t)b * NC * NHW + k;

    float acc[16];
#pragma unroll
    for (int j = 0; j < 16; ++j) acc[j] = 0.f;
#pragma unroll 8
    for (int c = 0; c < NC; ++c) {
        float v = xb[(size_t)c * NHW];
        const float* wr = Wt + c * 64 + o0;   // wave-uniform -> s_load
#pragma unroll
        for (int j = 0; j < 16; ++j)
            acc[j] = fmaf(wr[j], v, acc[j]);
    }
    float* xcb = xc + (size_t)b * NC * XCS + k;
#pragma unroll
    for (int j = 0; j < 16; ++j)
        xcb[(size_t)(o0 + j) * XCS] = acc[j];
}

// ---------------------------------------------------------------------------
// K2b: per-quarter histogram partials (batch min/max reduced from 64
// per-block partials).
// ---------------------------------------------------------------------------
__global__ __launch_bounds__(256) void k_hist(const double* __restrict__ S,
                                              const double* __restrict__ pmn,
                                              const double* __restrict__ pmx,
                                              double* __restrict__ pbins) {
    int blk = blockIdx.x, b = blk >> 2, part = blk & 3;
    int tid = threadIdx.x;
    __shared__ double sa, sz;
    if (tid < 64) {
        double mn = pmn[(b << 6) + tid], mx = pmx[(b << 6) + tid];
        for (int off = 32; off; off >>= 1) {
            mn = fmin(mn, __shfl_down(mn, off));
            mx = fmax(mx, __shfl_down(mx, off));
        }
        if (tid == 0) { sa = mn; sz = mx; }
    }
    __syncthreads();
    double a = sa, z = sz;
    double lv[NM];
#pragma unroll
    for (int m = 0; m < NM; ++m) lv[m] = a + (z - a) * ((double)m / 9.0);

    const double* Sb = S + (size_t)b * NHW + part * 4096;
    double bins[NM];
#pragma unroll
    for (int m = 0; m < NM; ++m) bins[m] = 0.0;
    for (int i = tid; i < 4096; i += 256) {
        double v = Sb[i];
#pragma unroll
        for (int m = 0; m < NM; ++m) {
            double d = fabs(lv[m] - v);
            if (d < 0.05) bins[m] += 1.0 - d;
        }
    }
#pragma unroll
    for (int m = 0; m < NM; ++m)
        for (int off = 32; off; off >>= 1) bins[m] += __shfl_down(bins[m], off);
    __shared__ double wb[4][NM];
    int wid = tid >> 6, lane = tid & 63;
    if (lane == 0) {
#pragma unroll
        for (int m = 0; m < NM; ++m) wb[wid][m] = bins[m];
    }
    __syncthreads();
    if (tid == 0) {
#pragma unroll
        for (int m = 0; m < NM; ++m)
            pbins[blk * NM + m] = wb[0][m] + wb[1][m] + wb[2][m] + wb[3][m];
    }
}

// ---------------------------------------------------------------------------
// K3: per-batch tail -> ratio/levels -> Cf -> P -> softmax -> Lp.
// ---------------------------------------------------------------------------
__global__ __launch_bounds__(256) void k_chain(
        const double* __restrict__ pmn, const double* __restrict__ pmx,
        const double* __restrict__ pbins,
        const float* __restrict__ fc1w, const float* __restrict__ fc1b,
        const float* __restrict__ ph1w, const float* __restrict__ ph1b,
        const float* __restrict__ ph2w, const float* __restrict__ ph2b,
        const float* __restrict__ ph3w, const float* __restrict__ ph3b,
        double* __restrict__ levelsOut, float* __restrict__ LpOut) {
    int b = blockIdx.x, tid = threadIdx.x;
    __shared__ double sa, sz;
    if (tid < 64) {
        double mn = pmn[(b << 6) + tid], mx = pmx[(b << 6) + tid];
        for (int off = 32; off; off >>= 1) {
            mn = fmin(mn, __shfl_down(mn, off));
            mx = fmax(mx, __shfl_down(mx, off));
        }
        if (tid == 0) { sa = mn; sz = mx; }
    }
    __syncthreads();
    __shared__ double levS[NM];
    __shared__ float ratio[NM];
    if (tid == 0) {
        double a = sa, z = sz;
        for (int m = 0; m < NM; ++m) levS[m] = a + (z - a) * ((double)m / 9.0);
        double den = 0.0;
        for (int m = 0; m < NM; ++m) {
            double cs = ((pbins[(4*b)*NM+m] + pbins[(4*b+1)*NM+m])
                        + pbins[(4*b+2)*NM+m]) + pbins[(4*b+3)*NM+m];
            den += cs;
            ratio[m] = (float)(cs / den);
        }
    }
    __syncthreads();

    __shared__ float CfL[640];
    for (int idx = tid; idx < 640; idx += 256) {
        int rm = idx >> 6, o = idx & 63;
        CfL[idx] = ratio[rm] * fc1w[o*2+0] + (float)levS[rm] * fc1w[o*2+1] + fc1b[o];
    }
    __syncthreads();

    __shared__ float P1[640], P2[640], P3[640];
    for (int idx = tid; idx < 640; idx += 256) {
        int o = idx / 10, m = idx - o * 10;
        float a1 = ph1b[o], a2 = ph2b[o], a3 = ph3b[o];
        for (int c2 = 0; c2 < NC; ++c2) {
            float cq = CfL[c2*10 + m];
            a1 = fmaf(ph1w[o*NC + c2], cq, a1);
            a2 = fmaf(ph2w[o*NC + c2], cq, a2);
            a3 = fmaf(ph3w[o*NC + c2], cq, a3);
        }
        P1[idx] = a1; P2[idx] = a2; P3[idx] = a3;
    }
    __syncthreads();

    __shared__ float XL[100];
    if (tid < 100) {
        int m = tid / 10, n = tid - (tid/10)*10;
        float acc = 0.f;
        for (int c2 = 0; c2 < NC; ++c2)
            acc = fmaf(P1[c2*10 + m], P2[c2*10 + n], acc);
        XL[tid] = acc;
    }
    __syncthreads();
    if (tid < NM) {
        float mxr = XL[tid*10];
        for (int n = 1; n < NM; ++n) mxr = fmaxf(mxr, XL[tid*10 + n]);
        float e[NM], sum = 0.f;
        for (int n = 0; n < NM; ++n) { e[n] = expf(XL[tid*10+n] - mxr); sum += e[n]; }
        for (int n = 0; n < NM; ++n) XL[tid*10+n] = e[n] / sum;
    }
    __syncthreads();

    for (int idx = tid; idx < 640; idx += 256) {
        int c2 = idx / 10, n = idx - (idx/10)*10;
        float acc = 0.f;
#pragma unroll
        for (int m = 0; m < NM; ++m) acc = fmaf(P3[c2*10 + m], XL[m*10 + n], acc);
        LpOut[b*640 + idx] = acc;
    }
    if (tid < NM) levelsOut[b*NM + tid] = levS[tid];
}

// ---------------------------------------------------------------------------
// K3b: per-pixel gather precompute (ONCE per pixel).  FROZEN.
// ---------------------------------------------------------------------------
__global__ __launch_bounds__(256) void k_vgath(
        const double* __restrict__ S, const double* __restrict__ levels,
        float* __restrict__ vg, float* __restrict__ Sf) {
    int P = blockIdx.x * 256 + threadIdx.x;
    int b = P >> 14, k = P & (NHW - 1);
    __shared__ double levL[NM];
    if (threadIdx.x < NM) levL[threadIdx.x] = levels[b*NM + threadIdx.x];
    __syncthreads();
    const double* Sb = S + (size_t)b * NHW;
    float* vgb = vg + (size_t)b * NM * NHW;
#pragma unroll
    for (int i = 0; i < NM; ++i) {
        int j = i * NHW + k;
        int p = j / 10;
        int m = j - p * 10;
        double d = fabs(levL[m] - Sb[p]);
        vgb[i * NHW + k] = (d < 0.05) ? (float)(1.0 - d) : 0.f;
    }
    Sf[P] = (float)Sb[k];
}

// ---------------------------------------------------------------------------
// K4: fused depthwise chain + final fusion, 32x64 output tiles (26 KB LDS).
// EXACT round-10 version (71.3 us: fp32 xc, XCS stride, expf sigmoid).
// ---------------------------------------------------------------------------
__global__ __launch_bounds__(256) void k_dwfinal(
        const float* __restrict__ xc, const float* __restrict__ x,
        const float* __restrict__ vg, const float* __restrict__ Sf,
        const float* __restrict__ Lp,
        const float* __restrict__ pw1, const float* __restrict__ pw2,
        const float* __restrict__ pw3, const float* __restrict__ pw4,
        const float* __restrict__ gamma, const float* __restrict__ beta,
        const float* __restrict__ bn1g, const float* __restrict__ bn1b,
        const float* __restrict__ bn2g, const float* __restrict__ bn2b,
        const float* __restrict__ wconv2, float* __restrict__ out) {
    int tile = blockIdx.x, c = blockIdx.y, b = blockIdx.z;
    int R0 = (tile >> 1) * 32, C0 = (tile & 1) * 64;
    const float inv = 0.9999950000374997f;   // 1/sqrt(1+1e-5)
    float s0 = gamma[0*NC+c]*inv, b0 = beta[0*NC+c];
    float s1 = gamma[1*NC+c]*inv, b1 = beta[1*NC+c];
    float s2 = gamma[2*NC+c]*inv, b2 = beta[2*NC+c];
    float s3 = gamma[3*NC+c]*inv, b3 = beta[3*NC+c];
    float s4 = gamma[4*NC+c]*inv, b4 = beta[4*NC+c];
    float w1[5], w2[5], w3[5], w4[5];
#pragma unroll
    for (int q = 0; q < 5; ++q) {
        w1[q] = pw1[c*5+q]; w2[q] = pw2[c*5+q];
        w3[q] = pw3[c*5+q]; w4[q] = pw4[c*5+q];
    }
    float Ac = wconv2[c] * (bn2g[c] * inv);
    float Bc = bn2b[c] + bn1b[c];
    float S1 = bn1g[c] * inv;

    __shared__ __align__(16) float A[44*76];   // 13.4 KB
    __shared__ __align__(16) float Bf[44*72];  // 12.7 KB
    __shared__ float LpL[NM];
    const float* src = xc + (size_t)(b*NC + c) * XCS;
    int tid = threadIdx.x;

    if (tid < NM) LpL[tid] = Lp[b*640 + c*10 + tid];

    // stage0: load + bn0 -> A[44][76], zeros outside image
    for (int t = tid; t < 44*19; t += 256) {
        int r = t / 19, g2 = t - r*19;
        int gy = R0 - 6 + r, gx0 = C0 - 6 + 4*g2;
        float4 v = make_float4(0.f, 0.f, 0.f, 0.f);
        bool rowOK = (unsigned)gy < NH;
        if (rowOK) {
            const float* rowp = src + gy*NW;
            if ((unsigned)gx0 <= (unsigned)(NW-4)) {
                v = *(const float4*)(rowp + gx0);
            } else {
                float* pv = (float*)&v;
#pragma unroll
                for (int u = 0; u < 4; ++u) {
                    int gx = gx0 + u;
                    if ((unsigned)gx < NW) pv[u] = rowp[gx];
                }
            }
        }
        float4 w;
        w.x = (rowOK && (unsigned)(gx0+0) < NW) ? fmaf(v.x, s0, b0) : 0.f;
        w.y = (rowOK && (unsigned)(gx0+1) < NW) ? fmaf(v.y, s0, b0) : 0.f;
        w.z = (rowOK && (unsigned)(gx0+2) < NW) ? fmaf(v.z, s0, b0) : 0.f;
        w.w = (rowOK && (unsigned)(gx0+3) < NW) ? fmaf(v.w, s0, b0) : 0.f;
        *(float4*)&A[r*76 + 4*g2] = w;
    }
    __syncthreads();

    // stage1: horizontal 1x5 (+-2) + bn1 -> Bf[44][72]
    for (int t = tid; t < 44*18; t += 256) {
        int r = t / 18, g2 = t - r*18;
        float xw[8];
        *(float4*)&xw[0] = *(float4*)&A[r*76 + 4*g2];
        *(float4*)&xw[4] = *(float4*)&A[r*76 + 4*g2 + 4];
        int gy = R0 - 6 + r;
        bool rowOK = (unsigned)gy < NH;
        float o[4];
#pragma unroll
        for (int u = 0; u < 4; ++u) {
            float acc = 0.f;
#pragma unroll
            for (int q = 0; q < 5; ++q) acc = fmaf(w1[q], xw[u+q], acc);
            int gx = C0 - 4 + 4*g2 + u;
            o[u] = (rowOK && (unsigned)gx < NW) ? fmaf(acc, s1, b1) : 0.f;
        }
        *(float4*)&Bf[r*72 + 4*g2] = *(float4*)o;
    }
    __syncthreads();

    // stage2: vertical 5x1 (+-2) + bn2 -> A[40][72]
    for (int t = tid; t < 40*18; t += 256) {
        int r = t / 18, g2 = t - r*18;
        float ys[5][4];
#pragma unroll
        for (int p = 0; p < 5; ++p)
            *(float4*)&ys[p][0] = *(float4*)&Bf[(r+p)*72 + 4*g2];
        int gy = R0 - 4 + r;
        bool rowOK = (unsigned)gy < NH;
        float o[4];
#pragma unroll
        for (int u = 0; u < 4; ++u) {
            float acc = 0.f;
#pragma unroll
            for (int p = 0; p < 5; ++p) acc = fmaf(w2[p], ys[p][u], acc);
            int gx = C0 - 4 + 4*g2 + u;
            o[u] = (rowOK && (unsigned)gx < NW) ? fmaf(acc, s2, b2) : 0.f;
        }
        *(float4*)&A[r*72 + 4*g2] = *(float4*)o;
    }
    __syncthreads();

    // stage3: horizontal 1x5 dil2 (+-4) + bn3 -> Bf[40][64]
    for (int t = tid; t < 40*16; t += 256) {
        int r = t >> 4, g2 = t & 15;
        float xw[12];
        *(float4*)&xw[0] = *(float4*)&A[r*72 + 4*g2];
        *(float4*)&xw[4] = *(float4*)&A[r*72 + 4*g2 + 4];
        *(float4*)&xw[8] = *(float4*)&A[r*72 + 4*g2 + 8];
        int gy = R0 - 4 + r;
        bool rowOK = (unsigned)gy < NH;
        float o[4];
#pragma unroll
        for (int u = 0; u < 4; ++u) {
            float acc = 0.f;
#pragma unroll
            for (int q = 0; q < 5; ++q) acc = fmaf(w3[q], xw[u+2*q], acc);
            o[u] = rowOK ? fmaf(acc, s3, b3) : 0.f;
        }
        *(float4*)&Bf[r*64 + 4*g2] = *(float4*)o;
    }
    __syncthreads();

    // stage4: vertical 5x1 dil2 (+-4) + bn4 -> x_center (regs), then fusion
    const float* vgb = vg + (size_t)b * NM * NHW;
    const float* Sfb = Sf + (size_t)b * NHW;
    for (int t = tid; t < 32*16; t += 256) {
        int r = t >> 4, g2 = t & 15;
        float ys[5][4];
#pragma unroll
        for (int p = 0; p < 5; ++p)
            *(float4*)&ys[p][0] = *(float4*)&Bf[(r+2*p)*64 + 4*g2];
        int kbase = (R0 + r) * NW + C0 + 4*g2;
        size_t xbase = (size_t)(b*NC + c) * NHW + kbase;
        float4 xv = *(const float4*)&x[xbase];
        float4 skv = *(const float4*)&Sfb[kbase];
        const float* xvp = (const float*)&xv;
        const float* skp = (const float*)&skv;
        float vr[NM][4];
#pragma unroll
        for (int i = 0; i < NM; ++i)
            *(float4*)&vr[i][0] = *(const float4*)&vgb[i * NHW + kbase];
        float res[4];
#pragma unroll
        for (int u = 0; u < 4; ++u) {
            float acc = 0.f;
#pragma unroll
            for (int p = 0; p < 5; ++p) acc = fmaf(w4[p], ys[p][u], acc);
            float xcen = fmaf(acc, s4, b4);
            float R = 0.f;
#pragma unroll
            for (int i = 0; i < NM; ++i) R = fmaf(LpL[i], vr[i][u], R);
            float pre = fmaf(Ac, skp[u], Bc) + S1 * R + xcen;
            float att = 1.0f / (1.0f + expf(-pre));
            res[u] = xvp[u] * att;
        }
        *(float4*)&out[xbase] = *(float4*)res;
    }
}

// ---------------------------------------------------------------------------
extern "C" void kernel_launch(void* const* d_in, const int* in_sizes, int n_in,
                              void* d_out, int out_size, void* d_ws, size_t ws_size,
                              hipStream_t stream) {
    (void)in_sizes; (void)n_in; (void)out_size; (void)ws_size;
    const float* x      = (const float*)d_in[0];
    const float* wconv1 = (const float*)d_in[1];
    const float* pw1    = (const float*)d_in[2];
    const float* pw2    = (const float*)d_in[3];
    const float* pw3    = (const float*)d_in[4];
    const float* pw4    = (const float*)d_in[5];
    const float* pgam   = (const float*)d_in[6];
    const float* pbet   = (const float*)d_in[7];
    const float* bn1g   = (const float*)d_in[8];
    const float* bn1b   = (const float*)d_in[9];
    const float* bn2g   = (const float*)d_in[10];
    const float* bn2b   = (const float*)d_in[11];
    const float* fc1w   = (const float*)d_in[12];
    const float* fc1b   = (const float*)d_in[13];
    const float* ph1w   = (const float*)d_in[14];
    const float* ph1b   = (const float*)d_in[15];
    const float* ph2w   = (const float*)d_in[16];
    const float* ph2b   = (const float*)d_in[17];
    const float* ph3w   = (const float*)d_in[18];
    const float* ph3b   = (const float*)d_in[19];
    const float* wconv2 = (const float*)d_in[20];
    float* out = (float*)d_out;

    // workspace layout (~81 MB), padded fp32 xc first, doubles 8B-aligned
    float*  ws    = (float*)d_ws;
    float*  xc    = ws;                                 // 1024*XCS f32 (67.2MB)
    double* Sd    = (double*)(ws + 1024 * XCS);         // 262144 f64 (2MB)
    double* g     = Sd + NB * NHW;                      // 1024 f64
    double* lev   = g + NB * NC;                        // 160 f64
    double* gn    = lev + NB * NM;                      // 16 f64
    double* pmn   = gn + NB;                            // 1024 f64
    double* pmx   = pmn + 1024;                         // 1024 f64
    double* pbins = pmx + 1024;                         // 640 f64
    float*  Lp    = (float*)(pbins + 640);              // 10240 f32
    float*  vg    = Lp + NB * 640;                      // 2621440 f32 (10.5MB)
    float*  Sf    = vg + NB * NM * NHW;                 // 262144 f32 (1MB)
    float*  Wt    = Sf + NB * NHW;                      // 4096 f32

    k_gmean<<<NB * NC, 256, 0, stream>>>(x, g);
    k_misc<<<17, 256, 0, stream>>>(wconv1, g, Wt, gn);
    k_S<<<NB * NHW / 256, 256, 0, stream>>>(x, g, gn, Sd, pmn, pmx);
    k_conv<<<dim3(NB * NHW / 256, 4), 256, 0, stream>>>(x, Wt, xc);
    k_hist<<<NB * 4, 256, 0, stream>>>(Sd, pmn, pmx, pbins);
    k_chain<<<NB, 256, 0, stream>>>(pmn, pmx, pbins, fc1w, fc1b,
                                    ph1w, ph1b, ph2w, ph2b, ph3w, ph3b,
                                    lev, Lp);
    k_vgath<<<NB * NHW / 256, 256, 0, stream>>>(Sd, lev, vg, Sf);
    k_dwfinal<<<dim3(8, NC, NB), 256, 0, stream>>>(
        xc, x, vg, Sf, Lp, pw1, pw2, pw3, pw4, pgam, pbet,
        bn1g, bn1b, bn2g, bn2b, wconv2, out);
}

// Round 14
// 156.549 us; speedup vs baseline: 1.1063x; 1.1063x over previous
//
#include <hip/hip_runtime.h>
#include <hip/hip_bf16.h>
#include <math.h>

// Problem constants: B=16, C=OUP=64, H=W=128, HW=16384, M=10
#define NB   16
#define NC   64
#define NH   128
#define NW   128
#define NHW  16384
#define NM   10
#define XCS  16416   // padded xc plane stride (elements)

// ---------------------------------------------------------------------------
// K0: g[b,c] = mean over HW of x[b,c,:,:]   (f64 accumulation, float4 loads)
// FROZEN (bit-exact g).
// ---------------------------------------------------------------------------
__global__ __launch_bounds__(256) void k_gmean(const float* __restrict__ x,
                                               double* __restrict__ g) {
    int bc = blockIdx.x;                     // 0..1023
    const float* xp = x + (size_t)bc * NHW;
    double s = 0.0;
    for (int i = threadIdx.x; i < NHW / 4; i += 256) {
        float4 v = ((const float4*)xp)[i];
        s += (double)v.x + (double)v.y + (double)v.z + (double)v.w;
    }
    for (int off = 32; off; off >>= 1) s += __shfl_down(s, off);
    __shared__ double red[4];
    int wid = threadIdx.x >> 6, lane = threadIdx.x & 63;
    if (lane == 0) red[wid] = s;
    __syncthreads();
    if (threadIdx.x == 0)
        g[bc] = (red[0] + red[1] + red[2] + red[3]) * (1.0 / (double)NHW);
}

// ---------------------------------------------------------------------------
// K0b: block 0 transposes W -> Wt[c][o]; blocks 1..16 compute gn[b].
// ---------------------------------------------------------------------------
__global__ __launch_bounds__(256) void k_misc(const float* __restrict__ W,
                                              const double* __restrict__ g,
                                              float* __restrict__ Wt,
                                              double* __restrict__ gn) {
    if (blockIdx.x == 0) {
        for (int e = threadIdx.x; e < 64 * 64; e += 256) {
            int c = e >> 6, o = e & 63;
            Wt[c * 64 + o] = W[o * 64 + c];
        }
    } else if (threadIdx.x == 0) {
        int b = blockIdx.x - 1;
        const double* gb = g + b * NC;
        double gsq = 0.0;
        for (int c = 0; c < NC; ++c) gsq += gb[c] * gb[c];
        gn[b] = fmax(sqrt(gsq), 1e-8);
    }
}

// ---------------------------------------------------------------------------
// K1: x_c = 1x1 conv + cosine-sim S + per-block S min/max partials.
// xv[64] in VGPRs; GEMM 4 passes x 16 outputs via wave-uniform s_load;
// fp32 xc stores to padded planes.  S arithmetic frozen (bit-identical).
// ---------------------------------------------------------------------------
__global__ __launch_bounds__(256, 4) void k_conv1_S(
        const float* __restrict__ x, const float* __restrict__ Wt,
        const double* __restrict__ g, const double* __restrict__ gn,
        float* __restrict__ xc, double* __restrict__ S,
        double* __restrict__ pmn, double* __restrict__ pmx) {
    int bid = blockIdx.x;
    int P = bid * 256 + threadIdx.x;
    int b = P >> 14, k = P & (NHW - 1);
    const float* xb = x + (size_t)b * NC * NHW + k;

    float xv[NC];
#pragma unroll
    for (int c = 0; c < NC; ++c) xv[c] = xb[(size_t)c * NHW];

    // S phase: same sequential f64 order as all passing rounds
    double Sv;
    {
        const double* gb = g + b * NC;
        double num = 0.0, sq = 0.0;
#pragma unroll
        for (int c = 0; c < NC; ++c) {
            double v = (double)xv[c];
            num += gb[c] * v;
            sq  += v * v;
        }
        double xn = fmax(sqrt(sq), 1e-8);
        Sv = num / (gn[b] * xn);
        S[P] = Sv;
    }

    // block min/max partials (fmin/fmax exact -> order-independent)
    {
        double mn = Sv, mx = Sv;
        for (int off = 32; off; off >>= 1) {
            mn = fmin(mn, __shfl_down(mn, off));
            mx = fmax(mx, __shfl_down(mx, off));
        }
        __shared__ double rmn[4], rmx[4];
        int wid = threadIdx.x >> 6, lane = threadIdx.x & 63;
        if (lane == 0) { rmn[wid] = mn; rmx[wid] = mx; }
        __syncthreads();
        if (threadIdx.x == 0) {
            pmn[bid] = fmin(fmin(rmn[0], rmn[1]), fmin(rmn[2], rmn[3]));
            pmx[bid] = fmax(fmax(rmx[0], rmx[1]), fmax(rmx[2], rmx[3]));
        }
    }

    // GEMM: 4 passes of 16 outputs; W wave-uniform -> s_load broadcast
    float* xcb = xc + (size_t)b * NC * XCS + k;
    for (int p = 0; p < 4; ++p) {
        int o0 = p * 16;
        float acc[16];
#pragma unroll
        for (int j = 0; j < 16; ++j) acc[j] = 0.f;
#pragma unroll
        for (int c = 0; c < NC; ++c) {
            const float* wr = Wt + c * 64 + o0;   // uniform -> s_load
#pragma unroll
            for (int j = 0; j < 16; ++j)
                acc[j] = fmaf(wr[j], xv[c], acc[j]);
        }
#pragma unroll
        for (int j = 0; j < 16; ++j)
            xcb[(size_t)(o0 + j) * XCS] = acc[j];
    }
}

// ---------------------------------------------------------------------------
// K3b: per-pixel gather precompute. Computes batch levels itself from the 64
// per-block min/max partials (same fmin/fmax reduce as k_chain -> levels
// bit-identical), then vg/Sf exactly as the frozen version.
// ---------------------------------------------------------------------------
__global__ __launch_bounds__(256) void k_vgath(
        const double* __restrict__ S,
        const double* __restrict__ pmn, const double* __restrict__ pmx,
        float* __restrict__ vg, float* __restrict__ Sf) {
    int P = blockIdx.x * 256 + threadIdx.x;
    int b = P >> 14, k = P & (NHW - 1);
    int tid = threadIdx.x;
    __shared__ double sa, sz;
    if (tid < 64) {
        double mn = pmn[(b << 6) + tid], mx = pmx[(b << 6) + tid];
        for (int off = 32; off; off >>= 1) {
            mn = fmin(mn, __shfl_down(mn, off));
            mx = fmax(mx, __shfl_down(mx, off));
        }
        if (tid == 0) { sa = mn; sz = mx; }
    }
    __syncthreads();
    __shared__ double levL[NM];
    if (tid == 0) {
        double a = sa, z = sz;
        for (int m = 0; m < NM; ++m) levL[m] = a + (z - a) * ((double)m / 9.0);
    }
    __syncthreads();
    const double* Sb = S + (size_t)b * NHW;
    float* vgb = vg + (size_t)b * NM * NHW;
#pragma unroll
    for (int i = 0; i < NM; ++i) {
        int j = i * NHW + k;
        int p = j / 10;
        int m = j - p * 10;
        double d = fabs(levL[m] - Sb[p]);
        vgb[i * NHW + k] = (d < 0.05) ? (float)(1.0 - d) : 0.f;
    }
    Sf[P] = (float)Sb[k];
}

// ---------------------------------------------------------------------------
// K2b: per-quarter histogram partials (batch min/max reduced from 64
// per-block partials -> exact same levels).
// ---------------------------------------------------------------------------
__global__ __launch_bounds__(256) void k_hist(const double* __restrict__ S,
                                              const double* __restrict__ pmn,
                                              const double* __restrict__ pmx,
                                              double* __restrict__ pbins) {
    int blk = blockIdx.x, b = blk >> 2, part = blk & 3;
    int tid = threadIdx.x;
    __shared__ double sa, sz;
    if (tid < 64) {
        double mn = pmn[(b << 6) + tid], mx = pmx[(b << 6) + tid];
        for (int off = 32; off; off >>= 1) {
            mn = fmin(mn, __shfl_down(mn, off));
            mx = fmax(mx, __shfl_down(mx, off));
        }
        if (tid == 0) { sa = mn; sz = mx; }
    }
    __syncthreads();
    double a = sa, z = sz;
    double lv[NM];
#pragma unroll
    for (int m = 0; m < NM; ++m) lv[m] = a + (z - a) * ((double)m / 9.0);

    const double* Sb = S + (size_t)b * NHW + part * 4096;
    double bins[NM];
#pragma unroll
    for (int m = 0; m < NM; ++m) bins[m] = 0.0;
    for (int i = tid; i < 4096; i += 256) {
        double v = Sb[i];
#pragma unroll
        for (int m = 0; m < NM; ++m) {
            double d = fabs(lv[m] - v);
            if (d < 0.05) bins[m] += 1.0 - d;
        }
    }
#pragma unroll
    for (int m = 0; m < NM; ++m)
        for (int off = 32; off; off >>= 1) bins[m] += __shfl_down(bins[m], off);
    __shared__ double wb[4][NM];
    int wid = tid >> 6, lane = tid & 63;
    if (lane == 0) {
#pragma unroll
        for (int m = 0; m < NM; ++m) wb[wid][m] = bins[m];
    }
    __syncthreads();
    if (tid == 0) {
#pragma unroll
        for (int m = 0; m < NM; ++m)
            pbins[blk * NM + m] = wb[0][m] + wb[1][m] + wb[2][m] + wb[3][m];
    }
}

// ---------------------------------------------------------------------------
// K3: per-batch tail -> ratio/levels -> Cf -> P -> softmax -> Lp.
// ---------------------------------------------------------------------------
__global__ __launch_bounds__(256) void k_chain(
        const double* __restrict__ pmn, const double* __restrict__ pmx,
        const double* __restrict__ pbins,
        const float* __restrict__ fc1w, const float* __restrict__ fc1b,
        const float* __restrict__ ph1w, const float* __restrict__ ph1b,
        const float* __restrict__ ph2w, const float* __restrict__ ph2b,
        const float* __restrict__ ph3w, const float* __restrict__ ph3b,
        double* __restrict__ levelsOut, float* __restrict__ LpOut) {
    int b = blockIdx.x, tid = threadIdx.x;
    __shared__ double sa, sz;
    if (tid < 64) {
        double mn = pmn[(b << 6) + tid], mx = pmx[(b << 6) + tid];
        for (int off = 32; off; off >>= 1) {
            mn = fmin(mn, __shfl_down(mn, off));
            mx = fmax(mx, __shfl_down(mx, off));
        }
        if (tid == 0) { sa = mn; sz = mx; }
    }
    __syncthreads();
    __shared__ double levS[NM];
    __shared__ float ratio[NM];
    if (tid == 0) {
        double a = sa, z = sz;
        for (int m = 0; m < NM; ++m) levS[m] = a + (z - a) * ((double)m / 9.0);
        double den = 0.0;
        for (int m = 0; m < NM; ++m) {
            double cs = ((pbins[(4*b)*NM+m] + pbins[(4*b+1)*NM+m])
                        + pbins[(4*b+2)*NM+m]) + pbins[(4*b+3)*NM+m];
            den += cs;
            ratio[m] = (float)(cs / den);
        }
    }
    __syncthreads();

    __shared__ float CfL[640];
    for (int idx = tid; idx < 640; idx += 256) {
        int rm = idx >> 6, o = idx & 63;
        CfL[idx] = ratio[rm] * fc1w[o*2+0] + (float)levS[rm] * fc1w[o*2+1] + fc1b[o];
    }
    __syncthreads();

    __shared__ float P1[640], P2[640], P3[640];
    for (int idx = tid; idx < 640; idx += 256) {
        int o = idx / 10, m = idx - o * 10;
        float a1 = ph1b[o], a2 = ph2b[o], a3 = ph3b[o];
        for (int c2 = 0; c2 < NC; ++c2) {
            float cq = CfL[c2*10 + m];
            a1 = fmaf(ph1w[o*NC + c2], cq, a1);
            a2 = fmaf(ph2w[o*NC + c2], cq, a2);
            a3 = fmaf(ph3w[o*NC + c2], cq, a3);
        }
        P1[idx] = a1; P2[idx] = a2; P3[idx] = a3;
    }
    __syncthreads();

    __shared__ float XL[100];
    if (tid < 100) {
        int m = tid / 10, n = tid - (tid/10)*10;
        float acc = 0.f;
        for (int c2 = 0; c2 < NC; ++c2)
            acc = fmaf(P1[c2*10 + m], P2[c2*10 + n], acc);
        XL[tid] = acc;
    }
    __syncthreads();
    if (tid < NM) {
        float mxr = XL[tid*10];
        for (int n = 1; n < NM; ++n) mxr = fmaxf(mxr, XL[tid*10 + n]);
        float e[NM], sum = 0.f;
        for (int n = 0; n < NM; ++n) { e[n] = expf(XL[tid*10+n] - mxr); sum += e[n]; }
        for (int n = 0; n < NM; ++n) XL[tid*10+n] = e[n] / sum;
    }
    __syncthreads();

    for (int idx = tid; idx < 640; idx += 256) {
        int c2 = idx / 10, n = idx - (idx/10)*10;
        float acc = 0.f;
#pragma unroll
        for (int m = 0; m < NM; ++m) acc = fmaf(P3[c2*10 + m], XL[m*10 + n], acc);
        LpOut[b*640 + idx] = acc;
    }
    if (tid < NM) levelsOut[b*NM + tid] = levS[tid];
}

// ---------------------------------------------------------------------------
// K4: fused depthwise chain + final fusion, 32x64 output tiles (26 KB LDS).
// EXACT round-10 version (71.3 us: fp32 xc, XCS stride, expf sigmoid).
// FROZEN — every restructure attempt (r4/r7/r8/r11/r12) regressed.
// ---------------------------------------------------------------------------
__global__ __launch_bounds__(256) void k_dwfinal(
        const float* __restrict__ xc, const float* __restrict__ x,
        const float* __restrict__ vg, const float* __restrict__ Sf,
        const float* __restrict__ Lp,
        const float* __restrict__ pw1, const float* __restrict__ pw2,
        const float* __restrict__ pw3, const float* __restrict__ pw4,
        const float* __restrict__ gamma, const float* __restrict__ beta,
        const float* __restrict__ bn1g, const float* __restrict__ bn1b,
        const float* __restrict__ bn2g, const float* __restrict__ bn2b,
        const float* __restrict__ wconv2, float* __restrict__ out) {
    int tile = blockIdx.x, c = blockIdx.y, b = blockIdx.z;
    int R0 = (tile >> 1) * 32, C0 = (tile & 1) * 64;
    const float inv = 0.9999950000374997f;   // 1/sqrt(1+1e-5)
    float s0 = gamma[0*NC+c]*inv, b0 = beta[0*NC+c];
    float s1 = gamma[1*NC+c]*inv, b1 = beta[1*NC+c];
    float s2 = gamma[2*NC+c]*inv, b2 = beta[2*NC+c];
    float s3 = gamma[3*NC+c]*inv, b3 = beta[3*NC+c];
    float s4 = gamma[4*NC+c]*inv, b4 = beta[4*NC+c];
    float w1[5], w2[5], w3[5], w4[5];
#pragma unroll
    for (int q = 0; q < 5; ++q) {
        w1[q] = pw1[c*5+q]; w2[q] = pw2[c*5+q];
        w3[q] = pw3[c*5+q]; w4[q] = pw4[c*5+q];
    }
    float Ac = wconv2[c] * (bn2g[c] * inv);
    float Bc = bn2b[c] + bn1b[c];
    float S1 = bn1g[c] * inv;

    __shared__ __align__(16) float A[44*76];   // 13.4 KB
    __shared__ __align__(16) float Bf[44*72];  // 12.7 KB
    __shared__ float LpL[NM];
    const float* src = xc + (size_t)(b*NC + c) * XCS;
    int tid = threadIdx.x;

    if (tid < NM) LpL[tid] = Lp[b*640 + c*10 + tid];

    // stage0: load + bn0 -> A[44][76], zeros outside image
    for (int t = tid; t < 44*19; t += 256) {
        int r = t / 19, g2 = t - r*19;
        int gy = R0 - 6 + r, gx0 = C0 - 6 + 4*g2;
        float4 v = make_float4(0.f, 0.f, 0.f, 0.f);
        bool rowOK = (unsigned)gy < NH;
        if (rowOK) {
            const float* rowp = src + gy*NW;
            if ((unsigned)gx0 <= (unsigned)(NW-4)) {
                v = *(const float4*)(rowp + gx0);
            } else {
                float* pv = (float*)&v;
#pragma unroll
                for (int u = 0; u < 4; ++u) {
                    int gx = gx0 + u;
                    if ((unsigned)gx < NW) pv[u] = rowp[gx];
                }
            }
        }
        float4 w;
        w.x = (rowOK && (unsigned)(gx0+0) < NW) ? fmaf(v.x, s0, b0) : 0.f;
        w.y = (rowOK && (unsigned)(gx0+1) < NW) ? fmaf(v.y, s0, b0) : 0.f;
        w.z = (rowOK && (unsigned)(gx0+2) < NW) ? fmaf(v.z, s0, b0) : 0.f;
        w.w = (rowOK && (unsigned)(gx0+3) < NW) ? fmaf(v.w, s0, b0) : 0.f;
        *(float4*)&A[r*76 + 4*g2] = w;
    }
    __syncthreads();

    // stage1: horizontal 1x5 (+-2) + bn1 -> Bf[44][72]
    for (int t = tid; t < 44*18; t += 256) {
        int r = t / 18, g2 = t - r*18;
        float xw[8];
        *(float4*)&xw[0] = *(float4*)&A[r*76 + 4*g2];
        *(float4*)&xw[4] = *(float4*)&A[r*76 + 4*g2 + 4];
        int gy = R0 - 6 + r;
        bool rowOK = (unsigned)gy < NH;
        float o[4];
#pragma unroll
        for (int u = 0; u < 4; ++u) {
            float acc = 0.f;
#pragma unroll
            for (int q = 0; q < 5; ++q) acc = fmaf(w1[q], xw[u+q], acc);
            int gx = C0 - 4 + 4*g2 + u;
            o[u] = (rowOK && (unsigned)gx < NW) ? fmaf(acc, s1, b1) : 0.f;
        }
        *(float4*)&Bf[r*72 + 4*g2] = *(float4*)o;
    }
    __syncthreads();

    // stage2: vertical 5x1 (+-2) + bn2 -> A[40][72]
    for (int t = tid; t < 40*18; t += 256) {
        int r = t / 18, g2 = t - r*18;
        float ys[5][4];
#pragma unroll
        for (int p = 0; p < 5; ++p)
            *(float4*)&ys[p][0] = *(float4*)&Bf[(r+p)*72 + 4*g2];
        int gy = R0 - 4 + r;
        bool rowOK = (unsigned)gy < NH;
        float o[4];
#pragma unroll
        for (int u = 0; u < 4; ++u) {
            float acc = 0.f;
#pragma unroll
            for (int p = 0; p < 5; ++p) acc = fmaf(w2[p], ys[p][u], acc);
            int gx = C0 - 4 + 4*g2 + u;
            o[u] = (rowOK && (unsigned)gx < NW) ? fmaf(acc, s2, b2) : 0.f;
        }
        *(float4*)&A[r*72 + 4*g2] = *(float4*)o;
    }
    __syncthreads();

    // stage3: horizontal 1x5 dil2 (+-4) + bn3 -> Bf[40][64]
    for (int t = tid; t < 40*16; t += 256) {
        int r = t >> 4, g2 = t & 15;
        float xw[12];
        *(float4*)&xw[0] = *(float4*)&A[r*72 + 4*g2];
        *(float4*)&xw[4] = *(float4*)&A[r*72 + 4*g2 + 4];
        *(float4*)&xw[8] = *(float4*)&A[r*72 + 4*g2 + 8];
        int gy = R0 - 4 + r;
        bool rowOK = (unsigned)gy < NH;
        float o[4];
#pragma unroll
        for (int u = 0; u < 4; ++u) {
            float acc = 0.f;
#pragma unroll
            for (int q = 0; q < 5; ++q) acc = fmaf(w3[q], xw[u+2*q], acc);
            o[u] = rowOK ? fmaf(acc, s3, b3) : 0.f;
        }
        *(float4*)&Bf[r*64 + 4*g2] = *(float4*)o;
    }
    __syncthreads();

    // stage4: vertical 5x1 dil2 (+-4) + bn4 -> x_center (regs), then fusion
    const float* vgb = vg + (size_t)b * NM * NHW;
    const float* Sfb = Sf + (size_t)b * NHW;
    for (int t = tid; t < 32*16; t += 256) {
        int r = t >> 4, g2 = t & 15;
        float ys[5][4];
#pragma unroll
        for (int p = 0; p < 5; ++p)
            *(float4*)&ys[p][0] = *(float4*)&Bf[(r+2*p)*64 + 4*g2];
        int kbase = (R0 + r) * NW + C0 + 4*g2;
        size_t xbase = (size_t)(b*NC + c) * NHW + kbase;
        float4 xv = *(const float4*)&x[xbase];
        float4 skv = *(const float4*)&Sfb[kbase];
        const float* xvp = (const float*)&xv;
        const float* skp = (const float*)&skv;
        float vr[NM][4];
#pragma unroll
        for (int i = 0; i < NM; ++i)
            *(float4*)&vr[i][0] = *(const float4*)&vgb[i * NHW + kbase];
        float res[4];
#pragma unroll
        for (int u = 0; u < 4; ++u) {
            float acc = 0.f;
#pragma unroll
            for (int p = 0; p < 5; ++p) acc = fmaf(w4[p], ys[p][u], acc);
            float xcen = fmaf(acc, s4, b4);
            float R = 0.f;
#pragma unroll
            for (int i = 0; i < NM; ++i) R = fmaf(LpL[i], vr[i][u], R);
            float pre = fmaf(Ac, skp[u], Bc) + S1 * R + xcen;
            float att = 1.0f / (1.0f + expf(-pre));
            res[u] = xvp[u] * att;
        }
        *(float4*)&out[xbase] = *(float4*)res;
    }
}

// ---------------------------------------------------------------------------
extern "C" void kernel_launch(void* const* d_in, const int* in_sizes, int n_in,
                              void* d_out, int out_size, void* d_ws, size_t ws_size,
                              hipStream_t stream) {
    (void)in_sizes; (void)n_in; (void)out_size; (void)ws_size;
    const float* x      = (const float*)d_in[0];
    const float* wconv1 = (const float*)d_in[1];
    const float* pw1    = (const float*)d_in[2];
    const float* pw2    = (const float*)d_in[3];
    const float* pw3    = (const float*)d_in[4];
    const float* pw4    = (const float*)d_in[5];
    const float* pgam   = (const float*)d_in[6];
    const float* pbet   = (const float*)d_in[7];
    const float* bn1g   = (const float*)d_in[8];
    const float* bn1b   = (const float*)d_in[9];
    const float* bn2g   = (const float*)d_in[10];
    const float* bn2b   = (const float*)d_in[11];
    const float* fc1w   = (const float*)d_in[12];
    const float* fc1b   = (const float*)d_in[13];
    const float* ph1w   = (const float*)d_in[14];
    const float* ph1b   = (const float*)d_in[15];
    const float* ph2w   = (const float*)d_in[16];
    const float* ph2b   = (const float*)d_in[17];
    const float* ph3w   = (const float*)d_in[18];
    const float* ph3b   = (const float*)d_in[19];
    const float* wconv2 = (const float*)d_in[20];
    float* out = (float*)d_out;

    // workspace layout (~81 MB), padded fp32 xc first, doubles 8B-aligned
    float*  ws    = (float*)d_ws;
    float*  xc    = ws;                                 // 1024*XCS f32 (67.2MB)
    double* Sd    = (double*)(ws + 1024 * XCS);         // 262144 f64 (2MB)
    double* g     = Sd + NB * NHW;                      // 1024 f64
    double* lev   = g + NB * NC;                        // 160 f64
    double* gn    = lev + NB * NM;                      // 16 f64
    double* pmn   = gn + NB;                            // 1024 f64
    double* pmx   = pmn + 1024;                         // 1024 f64
    double* pbins = pmx + 1024;                         // 640 f64
    float*  Lp    = (float*)(pbins + 640);              // 10240 f32
    float*  vg    = Lp + NB * 640;                      // 2621440 f32 (10.5MB)
    float*  Sf    = vg + NB * NM * NHW;                 // 262144 f32 (1MB)
    float*  Wt    = Sf + NB * NHW;                      // 4096 f32

    k_gmean<<<NB * NC, 256, 0, stream>>>(x, g);
    k_misc<<<17, 256, 0, stream>>>(wconv1, g, Wt, gn);
    k_conv1_S<<<NB * NHW / 256, 256, 0, stream>>>(x, Wt, g, gn, xc, Sd,
                                                  pmn, pmx);
    k_vgath<<<NB * NHW / 256, 256, 0, stream>>>(Sd, pmn, pmx, vg, Sf);
    k_hist<<<NB * 4, 256, 0, stream>>>(Sd, pmn, pmx, pbins);
    k_chain<<<NB, 256, 0, stream>>>(pmn, pmx, pbins, fc1w, fc1b,
                                    ph1w, ph1b, ph2w, ph2b, ph3w, ph3b,
                                    lev, Lp);
    k_dwfinal<<<dim3(8, NC, NB), 256, 0, stream>>>(
        xc, x, vg, Sf, Lp, pw1, pw2, pw3, pw4, pgam, pbet,
        bn1g, bn1b, bn2g, bn2b, wconv2, out);
}

// Round 15
// 152.980 us; speedup vs baseline: 1.1321x; 1.0233x over previous
//
#include <hip/hip_runtime.h>
#include <hip/hip_bf16.h>
#include <math.h>

// Problem constants: B=16, C=OUP=64, H=W=128, HW=16384, M=10
#define NB   16
#define NC   64
#define NH   128
#define NW   128
#define NHW  16384
#define NM   10
#define XCS  16416   // padded xc plane stride (elements)

// ---------------------------------------------------------------------------
// K0: g[b,c] = mean over HW of x[b,c,:,:]   (f64 accumulation, float4 loads)
// FROZEN (bit-exact g).
// ---------------------------------------------------------------------------
__global__ __launch_bounds__(256) void k_gmean(const float* __restrict__ x,
                                               double* __restrict__ g) {
    int bc = blockIdx.x;                     // 0..1023
    const float* xp = x + (size_t)bc * NHW;
    double s = 0.0;
    for (int i = threadIdx.x; i < NHW / 4; i += 256) {
        float4 v = ((const float4*)xp)[i];
        s += (double)v.x + (double)v.y + (double)v.z + (double)v.w;
    }
    for (int off = 32; off; off >>= 1) s += __shfl_down(s, off);
    __shared__ double red[4];
    int wid = threadIdx.x >> 6, lane = threadIdx.x & 63;
    if (lane == 0) red[wid] = s;
    __syncthreads();
    if (threadIdx.x == 0)
        g[bc] = (red[0] + red[1] + red[2] + red[3]) * (1.0 / (double)NHW);
}

// ---------------------------------------------------------------------------
// K0b: block 0 transposes W -> Wt[c][o]; blocks 1..16 compute gn[b].
// ---------------------------------------------------------------------------
__global__ __launch_bounds__(256) void k_misc(const float* __restrict__ W,
                                              const double* __restrict__ g,
                                              float* __restrict__ Wt,
                                              double* __restrict__ gn) {
    if (blockIdx.x == 0) {
        for (int e = threadIdx.x; e < 64 * 64; e += 256) {
            int c = e >> 6, o = e & 63;
            Wt[c * 64 + o] = W[o * 64 + c];
        }
    } else if (threadIdx.x == 0) {
        int b = blockIdx.x - 1;
        const double* gb = g + b * NC;
        double gsq = 0.0;
        for (int c = 0; c < NC; ++c) gsq += gb[c] * gb[c];
        gn[b] = fmax(sqrt(gsq), 1e-8);
    }
}

// ---------------------------------------------------------------------------
// K1: x_c = 1x1 conv + cosine-sim S + per-block S min/max partials.
// FROZEN structure (r14). xv[64] in VGPRs; GEMM 4 passes x 16 outputs via
// wave-uniform s_load; fp32 xc to padded planes; S arithmetic bit-identical.
// ---------------------------------------------------------------------------
__global__ __launch_bounds__(256, 4) void k_conv1_S(
        const float* __restrict__ x, const float* __restrict__ Wt,
        const double* __restrict__ g, const double* __restrict__ gn,
        float* __restrict__ xc, double* __restrict__ S,
        double* __restrict__ pmn, double* __restrict__ pmx) {
    int bid = blockIdx.x;
    int P = bid * 256 + threadIdx.x;
    int b = P >> 14, k = P & (NHW - 1);
    const float* xb = x + (size_t)b * NC * NHW + k;

    float xv[NC];
#pragma unroll
    for (int c = 0; c < NC; ++c) xv[c] = xb[(size_t)c * NHW];

    // S phase: same sequential f64 order as all passing rounds
    double Sv;
    {
        const double* gb = g + b * NC;
        double num = 0.0, sq = 0.0;
#pragma unroll
        for (int c = 0; c < NC; ++c) {
            double v = (double)xv[c];
            num += gb[c] * v;
            sq  += v * v;
        }
        double xn = fmax(sqrt(sq), 1e-8);
        Sv = num / (gn[b] * xn);
        S[P] = Sv;
    }

    // block min/max partials (fmin/fmax exact -> order-independent)
    {
        double mn = Sv, mx = Sv;
        for (int off = 32; off; off >>= 1) {
            mn = fmin(mn, __shfl_down(mn, off));
            mx = fmax(mx, __shfl_down(mx, off));
        }
        __shared__ double rmn[4], rmx[4];
        int wid = threadIdx.x >> 6, lane = threadIdx.x & 63;
        if (lane == 0) { rmn[wid] = mn; rmx[wid] = mx; }
        __syncthreads();
        if (threadIdx.x == 0) {
            pmn[bid] = fmin(fmin(rmn[0], rmn[1]), fmin(rmn[2], rmn[3]));
            pmx[bid] = fmax(fmax(rmx[0], rmx[1]), fmax(rmx[2], rmx[3]));
        }
    }

    // GEMM: 4 passes of 16 outputs; W wave-uniform -> s_load broadcast
    float* xcb = xc + (size_t)b * NC * XCS + k;
    for (int p = 0; p < 4; ++p) {
        int o0 = p * 16;
        float acc[16];
#pragma unroll
        for (int j = 0; j < 16; ++j) acc[j] = 0.f;
#pragma unroll
        for (int c = 0; c < NC; ++c) {
            const float* wr = Wt + c * 64 + o0;   // uniform -> s_load
#pragma unroll
            for (int j = 0; j < 16; ++j)
                acc[j] = fmaf(wr[j], xv[c], acc[j]);
        }
#pragma unroll
        for (int j = 0; j < 16; ++j)
            xcb[(size_t)(o0 + j) * XCS] = acc[j];
    }
}

// ---------------------------------------------------------------------------
// K3b: per-pixel gather precompute + FUSED histogram partials.
// Levels computed from the 64 per-block min/max partials (bit-identical
// fmin/fmax reduce). Each thread's pixel value Sk contributes its 10 bin
// terms (same f64 math as the old k_hist; only summation ORDER differs,
// which feeds the continuous ratio path only). Writes pbins[bid][10].
// ---------------------------------------------------------------------------
__global__ __launch_bounds__(256) void k_vgath(
        const double* __restrict__ S,
        const double* __restrict__ pmn, const double* __restrict__ pmx,
        float* __restrict__ vg, float* __restrict__ Sf,
        double* __restrict__ pbins) {
    int bid = blockIdx.x;
    int P = bid * 256 + threadIdx.x;
    int b = P >> 14, k = P & (NHW - 1);
    int tid = threadIdx.x;
    __shared__ double sa, sz;
    if (tid < 64) {
        double mn = pmn[(b << 6) + tid], mx = pmx[(b << 6) + tid];
        for (int off = 32; off; off >>= 1) {
            mn = fmin(mn, __shfl_down(mn, off));
            mx = fmax(mx, __shfl_down(mx, off));
        }
        if (tid == 0) { sa = mn; sz = mx; }
    }
    __syncthreads();
    __shared__ double levL[NM];
    if (tid == 0) {
        double a = sa, z = sz;
        for (int m = 0; m < NM; ++m) levL[m] = a + (z - a) * ((double)m / 9.0);
    }
    __syncthreads();

    const double* Sb = S + (size_t)b * NHW;
    float* vgb = vg + (size_t)b * NM * NHW;
#pragma unroll
    for (int i = 0; i < NM; ++i) {
        int j = i * NHW + k;
        int p = j / 10;
        int m = j - p * 10;
        double d = fabs(levL[m] - Sb[p]);
        vgb[i * NHW + k] = (d < 0.05) ? (float)(1.0 - d) : 0.f;
    }
    double Sk = Sb[k];
    Sf[P] = (float)Sk;

    // histogram contribution of this pixel (f64, same comparisons as before)
    double bins[NM];
#pragma unroll
    for (int m = 0; m < NM; ++m) {
        double d = fabs(levL[m] - Sk);
        bins[m] = (d < 0.05) ? (1.0 - d) : 0.0;
    }
#pragma unroll
    for (int m = 0; m < NM; ++m)
        for (int off = 32; off; off >>= 1) bins[m] += __shfl_down(bins[m], off);
    __shared__ double wb[4][NM];
    int wid = tid >> 6, lane = tid & 63;
    if (lane == 0) {
#pragma unroll
        for (int m = 0; m < NM; ++m) wb[wid][m] = bins[m];
    }
    __syncthreads();
    if (tid == 0) {
#pragma unroll
        for (int m = 0; m < NM; ++m)
            pbins[bid * NM + m] = wb[0][m] + wb[1][m] + wb[2][m] + wb[3][m];
    }
}

// ---------------------------------------------------------------------------
// K3: per-batch tail -> ratio/levels -> Cf -> P -> softmax -> Lp.
// Reduces 64 per-block bin partials per batch.
// ---------------------------------------------------------------------------
__global__ __launch_bounds__(256) void k_chain(
        const double* __restrict__ pmn, const double* __restrict__ pmx,
        const double* __restrict__ pbins,
        const float* __restrict__ fc1w, const float* __restrict__ fc1b,
        const float* __restrict__ ph1w, const float* __restrict__ ph1b,
        const float* __restrict__ ph2w, const float* __restrict__ ph2b,
        const float* __restrict__ ph3w, const float* __restrict__ ph3b,
        float* __restrict__ LpOut) {
    int b = blockIdx.x, tid = threadIdx.x;
    __shared__ double sa, sz;
    if (tid < 64) {
        double mn = pmn[(b << 6) + tid], mx = pmx[(b << 6) + tid];
        for (int off = 32; off; off >>= 1) {
            mn = fmin(mn, __shfl_down(mn, off));
            mx = fmax(mx, __shfl_down(mx, off));
        }
        if (tid == 0) { sa = mn; sz = mx; }
    }
    __syncthreads();
    // parallel partial-bin reduce: 64 partials x 10 bins
    __shared__ double binS[NM];
    if (tid < 64) {
        const double* pb = pbins + (size_t)(b << 6) * NM;
#pragma unroll
        for (int m = 0; m < NM; ++m) {
            double s = pb[tid * NM + m];
            for (int off = 32; off; off >>= 1) s += __shfl_down(s, off);
            if (tid == 0) binS[m] = s;
        }
    }
    __syncthreads();
    __shared__ double levS[NM];
    __shared__ float ratio[NM];
    if (tid == 0) {
        double a = sa, z = sz;
        for (int m = 0; m < NM; ++m) levS[m] = a + (z - a) * ((double)m / 9.0);
        double den = 0.0;
        for (int m = 0; m < NM; ++m) {
            den += binS[m];
            ratio[m] = (float)(binS[m] / den);
        }
    }
    __syncthreads();

    __shared__ float CfL[640];
    for (int idx = tid; idx < 640; idx += 256) {
        int rm = idx >> 6, o = idx & 63;
        CfL[idx] = ratio[rm] * fc1w[o*2+0] + (float)levS[rm] * fc1w[o*2+1] + fc1b[o];
    }
    __syncthreads();

    __shared__ float P1[640], P2[640], P3[640];
    for (int idx = tid; idx < 640; idx += 256) {
        int o = idx / 10, m = idx - o * 10;
        float a1 = ph1b[o], a2 = ph2b[o], a3 = ph3b[o];
        for (int c2 = 0; c2 < NC; ++c2) {
            float cq = CfL[c2*10 + m];
            a1 = fmaf(ph1w[o*NC + c2], cq, a1);
            a2 = fmaf(ph2w[o*NC + c2], cq, a2);
            a3 = fmaf(ph3w[o*NC + c2], cq, a3);
        }
        P1[idx] = a1; P2[idx] = a2; P3[idx] = a3;
    }
    __syncthreads();

    __shared__ float XL[100];
    if (tid < 100) {
        int m = tid / 10, n = tid - (tid/10)*10;
        float acc = 0.f;
        for (int c2 = 0; c2 < NC; ++c2)
            acc = fmaf(P1[c2*10 + m], P2[c2*10 + n], acc);
        XL[tid] = acc;
    }
    __syncthreads();
    if (tid < NM) {
        float mxr = XL[tid*10];
        for (int n = 1; n < NM; ++n) mxr = fmaxf(mxr, XL[tid*10 + n]);
        float e[NM], sum = 0.f;
        for (int n = 0; n < NM; ++n) { e[n] = expf(XL[tid*10+n] - mxr); sum += e[n]; }
        for (int n = 0; n < NM; ++n) XL[tid*10+n] = e[n] / sum;
    }
    __syncthreads();

    for (int idx = tid; idx < 640; idx += 256) {
        int c2 = idx / 10, n = idx - (idx/10)*10;
        float acc = 0.f;
#pragma unroll
        for (int m = 0; m < NM; ++m) acc = fmaf(P3[c2*10 + m], XL[m*10 + n], acc);
        LpOut[b*640 + idx] = acc;
    }
}

// ---------------------------------------------------------------------------
// K4: fused depthwise chain + final fusion, 32x64 output tiles (26 KB LDS).
// EXACT round-10 version (71.3 us). FROZEN — every restructure regressed.
// ---------------------------------------------------------------------------
__global__ __launch_bounds__(256) void k_dwfinal(
        const float* __restrict__ xc, const float* __restrict__ x,
        const float* __restrict__ vg, const float* __restrict__ Sf,
        const float* __restrict__ Lp,
        const float* __restrict__ pw1, const float* __restrict__ pw2,
        const float* __restrict__ pw3, const float* __restrict__ pw4,
        const float* __restrict__ gamma, const float* __restrict__ beta,
        const float* __restrict__ bn1g, const float* __restrict__ bn1b,
        const float* __restrict__ bn2g, const float* __restrict__ bn2b,
        const float* __restrict__ wconv2, float* __restrict__ out) {
    int tile = blockIdx.x, c = blockIdx.y, b = blockIdx.z;
    int R0 = (tile >> 1) * 32, C0 = (tile & 1) * 64;
    const float inv = 0.9999950000374997f;   // 1/sqrt(1+1e-5)
    float s0 = gamma[0*NC+c]*inv, b0 = beta[0*NC+c];
    float s1 = gamma[1*NC+c]*inv, b1 = beta[1*NC+c];
    float s2 = gamma[2*NC+c]*inv, b2 = beta[2*NC+c];
    float s3 = gamma[3*NC+c]*inv, b3 = beta[3*NC+c];
    float s4 = gamma[4*NC+c]*inv, b4 = beta[4*NC+c];
    float w1[5], w2[5], w3[5], w4[5];
#pragma unroll
    for (int q = 0; q < 5; ++q) {
        w1[q] = pw1[c*5+q]; w2[q] = pw2[c*5+q];
        w3[q] = pw3[c*5+q]; w4[q] = pw4[c*5+q];
    }
    float Ac = wconv2[c] * (bn2g[c] * inv);
    float Bc = bn2b[c] + bn1b[c];
    float S1 = bn1g[c] * inv;

    __shared__ __align__(16) float A[44*76];   // 13.4 KB
    __shared__ __align__(16) float Bf[44*72];  // 12.7 KB
    __shared__ float LpL[NM];
    const float* src = xc + (size_t)(b*NC + c) * XCS;
    int tid = threadIdx.x;

    if (tid < NM) LpL[tid] = Lp[b*640 + c*10 + tid];

    // stage0: load + bn0 -> A[44][76], zeros outside image
    for (int t = tid; t < 44*19; t += 256) {
        int r = t / 19, g2 = t - r*19;
        int gy = R0 - 6 + r, gx0 = C0 - 6 + 4*g2;
        float4 v = make_float4(0.f, 0.f, 0.f, 0.f);
        bool rowOK = (unsigned)gy < NH;
        if (rowOK) {
            const float* rowp = src + gy*NW;
            if ((unsigned)gx0 <= (unsigned)(NW-4)) {
                v = *(const float4*)(rowp + gx0);
            } else {
                float* pv = (float*)&v;
#pragma unroll
                for (int u = 0; u < 4; ++u) {
                    int gx = gx0 + u;
                    if ((unsigned)gx < NW) pv[u] = rowp[gx];
                }
            }
        }
        float4 w;
        w.x = (rowOK && (unsigned)(gx0+0) < NW) ? fmaf(v.x, s0, b0) : 0.f;
        w.y = (rowOK && (unsigned)(gx0+1) < NW) ? fmaf(v.y, s0, b0) : 0.f;
        w.z = (rowOK && (unsigned)(gx0+2) < NW) ? fmaf(v.z, s0, b0) : 0.f;
        w.w = (rowOK && (unsigned)(gx0+3) < NW) ? fmaf(v.w, s0, b0) : 0.f;
        *(float4*)&A[r*76 + 4*g2] = w;
    }
    __syncthreads();

    // stage1: horizontal 1x5 (+-2) + bn1 -> Bf[44][72]
    for (int t = tid; t < 44*18; t += 256) {
        int r = t / 18, g2 = t - r*18;
        float xw[8];
        *(float4*)&xw[0] = *(float4*)&A[r*76 + 4*g2];
        *(float4*)&xw[4] = *(float4*)&A[r*76 + 4*g2 + 4];
        int gy = R0 - 6 + r;
        bool rowOK = (unsigned)gy < NH;
        float o[4];
#pragma unroll
        for (int u = 0; u < 4; ++u) {
            float acc = 0.f;
#pragma unroll
            for (int q = 0; q < 5; ++q) acc = fmaf(w1[q], xw[u+q], acc);
            int gx = C0 - 4 + 4*g2 + u;
            o[u] = (rowOK && (unsigned)gx < NW) ? fmaf(acc, s1, b1) : 0.f;
        }
        *(float4*)&Bf[r*72 + 4*g2] = *(float4*)o;
    }
    __syncthreads();

    // stage2: vertical 5x1 (+-2) + bn2 -> A[40][72]
    for (int t = tid; t < 40*18; t += 256) {
        int r = t / 18, g2 = t - r*18;
        float ys[5][4];
#pragma unroll
        for (int p = 0; p < 5; ++p)
            *(float4*)&ys[p][0] = *(float4*)&Bf[(r+p)*72 + 4*g2];
        int gy = R0 - 4 + r;
        bool rowOK = (unsigned)gy < NH;
        float o[4];
#pragma unroll
        for (int u = 0; u < 4; ++u) {
            float acc = 0.f;
#pragma unroll
            for (int p = 0; p < 5; ++p) acc = fmaf(w2[p], ys[p][u], acc);
            int gx = C0 - 4 + 4*g2 + u;
            o[u] = (rowOK && (unsigned)gx < NW) ? fmaf(acc, s2, b2) : 0.f;
        }
        *(float4*)&A[r*72 + 4*g2] = *(float4*)o;
    }
    __syncthreads();

    // stage3: horizontal 1x5 dil2 (+-4) + bn3 -> Bf[40][64]
    for (int t = tid; t < 40*16; t += 256) {
        int r = t >> 4, g2 = t & 15;
        float xw[12];
        *(float4*)&xw[0] = *(float4*)&A[r*72 + 4*g2];
        *(float4*)&xw[4] = *(float4*)&A[r*72 + 4*g2 + 4];
        *(float4*)&xw[8] = *(float4*)&A[r*72 + 4*g2 + 8];
        int gy = R0 - 4 + r;
        bool rowOK = (unsigned)gy < NH;
        float o[4];
#pragma unroll
        for (int u = 0; u < 4; ++u) {
            float acc = 0.f;
#pragma unroll
            for (int q = 0; q < 5; ++q) acc = fmaf(w3[q], xw[u+2*q], acc);
            o[u] = rowOK ? fmaf(acc, s3, b3) : 0.f;
        }
        *(float4*)&Bf[r*64 + 4*g2] = *(float4*)o;
    }
    __syncthreads();

    // stage4: vertical 5x1 dil2 (+-4) + bn4 -> x_center (regs), then fusion
    const float* vgb = vg + (size_t)b * NM * NHW;
    const float* Sfb = Sf + (size_t)b * NHW;
    for (int t = tid; t < 32*16; t += 256) {
        int r = t >> 4, g2 = t & 15;
        float ys[5][4];
#pragma unroll
        for (int p = 0; p < 5; ++p)
            *(float4*)&ys[p][0] = *(float4*)&Bf[(r+2*p)*64 + 4*g2];
        int kbase = (R0 + r) * NW + C0 + 4*g2;
        size_t xbase = (size_t)(b*NC + c) * NHW + kbase;
        float4 xv = *(const float4*)&x[xbase];
        float4 skv = *(const float4*)&Sfb[kbase];
        const float* xvp = (const float*)&xv;
        const float* skp = (const float*)&skv;
        float vr[NM][4];
#pragma unroll
        for (int i = 0; i < NM; ++i)
            *(float4*)&vr[i][0] = *(const float4*)&vgb[i * NHW + kbase];
        float res[4];
#pragma unroll
        for (int u = 0; u < 4; ++u) {
            float acc = 0.f;
#pragma unroll
            for (int p = 0; p < 5; ++p) acc = fmaf(w4[p], ys[p][u], acc);
            float xcen = fmaf(acc, s4, b4);
            float R = 0.f;
#pragma unroll
            for (int i = 0; i < NM; ++i) R = fmaf(LpL[i], vr[i][u], R);
            float pre = fmaf(Ac, skp[u], Bc) + S1 * R + xcen;
            float att = 1.0f / (1.0f + expf(-pre));
            res[u] = xvp[u] * att;
        }
        *(float4*)&out[xbase] = *(float4*)res;
    }
}

// ---------------------------------------------------------------------------
extern "C" void kernel_launch(void* const* d_in, const int* in_sizes, int n_in,
                              void* d_out, int out_size, void* d_ws, size_t ws_size,
                              hipStream_t stream) {
    (void)in_sizes; (void)n_in; (void)out_size; (void)ws_size;
    const float* x      = (const float*)d_in[0];
    const float* wconv1 = (const float*)d_in[1];
    const float* pw1    = (const float*)d_in[2];
    const float* pw2    = (const float*)d_in[3];
    const float* pw3    = (const float*)d_in[4];
    const float* pw4    = (const float*)d_in[5];
    const float* pgam   = (const float*)d_in[6];
    const float* pbet   = (const float*)d_in[7];
    const float* bn1g   = (const float*)d_in[8];
    const float* bn1b   = (const float*)d_in[9];
    const float* bn2g   = (const float*)d_in[10];
    const float* bn2b   = (const float*)d_in[11];
    const float* fc1w   = (const float*)d_in[12];
    const float* fc1b   = (const float*)d_in[13];
    const float* ph1w   = (const float*)d_in[14];
    const float* ph1b   = (const float*)d_in[15];
    const float* ph2w   = (const float*)d_in[16];
    const float* ph2b   = (const float*)d_in[17];
    const float* ph3w   = (const float*)d_in[18];
    const float* ph3b   = (const float*)d_in[19];
    const float* wconv2 = (const float*)d_in[20];
    float* out = (float*)d_out;

    // workspace layout (~81 MB), padded fp32 xc first, doubles 8B-aligned
    float*  ws    = (float*)d_ws;
    float*  xc    = ws;                                 // 1024*XCS f32 (67.2MB)
    double* Sd    = (double*)(ws + 1024 * XCS);         // 262144 f64 (2MB)
    double* g     = Sd + NB * NHW;                      // 1024 f64
    double* gn    = g + NB * NC;                        // 16 f64
    double* pmn   = gn + NB;                            // 1024 f64
    double* pmx   = pmn + 1024;                         // 1024 f64
    double* pbins = pmx + 1024;                         // 10240 f64 (80KB)
    float*  Lp    = (float*)(pbins + 1024 * NM);        // 10240 f32
    float*  vg    = Lp + NB * 640;                      // 2621440 f32 (10.5MB)
    float*  Sf    = vg + NB * NM * NHW;                 // 262144 f32 (1MB)
    float*  Wt    = Sf + NB * NHW;                      // 4096 f32

    k_gmean<<<NB * NC, 256, 0, stream>>>(x, g);
    k_misc<<<17, 256, 0, stream>>>(wconv1, g, Wt, gn);
    k_conv1_S<<<NB * NHW / 256, 256, 0, stream>>>(x, Wt, g, gn, xc, Sd,
                                                  pmn, pmx);
    k_vgath<<<NB * NHW / 256, 256, 0, stream>>>(Sd, pmn, pmx, vg, Sf, pbins);
    k_chain<<<NB, 256, 0, stream>>>(pmn, pmx, pbins, fc1w, fc1b,
                                    ph1w, ph1b, ph2w, ph2b, ph3w, ph3b, Lp);
    k_dwfinal<<<dim3(8, NC, NB), 256, 0, stream>>>(
        xc, x, vg, Sf, Lp, pw1, pw2, pw3, pw4, pgam, pbet,
        bn1g, bn1b, bn2g, bn2b, wconv2, out);
}